// Round 8
// baseline (978.894 us; speedup 1.0000x reference)
//
#include <hip/hip_runtime.h>
#include <hip/hip_bf16.h>

// SSM h_t = A h_{t-1} + B^T x_t via stride-doubling over time, window 16:
//   U = X @ B;  u^k[t] = u^{k-1}[t] + u^{k-1}[t-s] @ (A^s)^T, s = 1,2,4,8
//   h = u^4  (+ O(||A^16||) truncation, bit-invisible vs bf16 noise)
// Big GEMMs (16384x2048x2048): m97 128^2/BK=64 loop at (256,4) + XCD swizzle
//   (r7: 884 TF), this round switched to mfma_f32_32x32x16_bf16 (m119: 2495
//   vs 2176 TF pipe rate, half the MFMA instruction count).
// Squarings (2048^3): 64^2-tile (256,4) kernel -> 1024 blocks = 4/CU TLP
//   (was 256 blocks = 1/CU, no m114 cover), verified 16x16 fragments.

typedef __attribute__((ext_vector_type(8))) short bf16x8_t;
typedef __attribute__((ext_vector_type(4))) float f32x4_t;
typedef __attribute__((ext_vector_type(16))) float f32x16_t;
typedef __attribute__((ext_vector_type(4))) float float4_t;
typedef __attribute__((ext_vector_type(4))) unsigned short ushort4_t;

#define TDIM 16384
#define HDIM 2048

__device__ __forceinline__ unsigned short f2bf(float f) {
  unsigned int x = __builtin_bit_cast(unsigned int, f);
  x += 0x7fffu + ((x >> 16) & 1u);
  return (unsigned short)(x >> 16);
}
__device__ __forceinline__ float bf2f(unsigned short u) {
  unsigned int x = ((unsigned int)u) << 16;
  return __builtin_bit_cast(float, x);
}

__global__ void cast_f32_bf16_k(const float* __restrict__ in,
                                unsigned short* __restrict__ out, int n4) {
  int i = blockIdx.x * blockDim.x + threadIdx.x;
  const int stride = gridDim.x * blockDim.x;
  for (; i < n4; i += stride) {
    float4_t v = ((const float4_t*)in)[i];
    ushort4_t o;
    o[0] = f2bf(v[0]); o[1] = f2bf(v[1]); o[2] = f2bf(v[2]); o[3] = f2bf(v[3]);
    ((ushort4_t*)out)[i] = o;
  }
}

__global__ void transpose_cast_f32_k(const float* __restrict__ in,
                                     unsigned short* __restrict__ out, int n) {
  __shared__ unsigned short tile[32][33];
  const int tx = threadIdx.x & 31, ty = threadIdx.x >> 5;
  const int bx = blockIdx.x * 32, by = blockIdx.y * 32;
#pragma unroll
  for (int j = 0; j < 32; j += 8)
    tile[ty + j][tx] = f2bf(in[(size_t)(by + ty + j) * n + bx + tx]);
  __syncthreads();
#pragma unroll
  for (int j = 0; j < 32; j += 8)
    out[(size_t)(bx + ty + j) * n + by + tx] = tile[tx][ty + j];
}

__global__ void transpose_bf16_k(const unsigned short* __restrict__ in,
                                 unsigned short* __restrict__ out, int n) {
  __shared__ unsigned short tile[32][33];
  const int tx = threadIdx.x & 31, ty = threadIdx.x >> 5;
  const int bx = blockIdx.x * 32, by = blockIdx.y * 32;
#pragma unroll
  for (int j = 0; j < 32; j += 8)
    tile[ty + j][tx] = in[(size_t)(by + ty + j) * n + bx + tx];
  __syncthreads();
#pragma unroll
  for (int j = 0; j < 32; j += 8)
    out[(size_t)(bx + ty + j) * n + by + tx] = tile[tx][ty + j];
}

#define GLL(SRC, DST)                                                          \
  __builtin_amdgcn_global_load_lds(                                            \
      (const __attribute__((address_space(1))) unsigned int*)(SRC),            \
      (__attribute__((address_space(3))) unsigned int*)(DST), 16, 0, 0)

// ------------- 64^2-tile kernel, (256,4): H x H squarings -------------
// 4 waves (2x2), wave-tile 32x32 = 2x2 fragments of 16x16x32 (verified
// layout). Single-buffered BK=64; 1024 blocks -> 4 blocks/CU TLP cover.
template <int CD_F32>
__global__ __launch_bounds__(256, 4)
void gemm64_k(const unsigned short* __restrict__ Aop,
              const unsigned short* __restrict__ BT,
              void* __restrict__ Cout, int N, int K) {
  __shared__ unsigned short Atile[64 * 64];
  __shared__ unsigned short Btile[64 * 64];
  const int tid = threadIdx.x;
  const int lane = tid & 63;
  const int w = tid >> 6;
  const int wr = w >> 1, wc = w & 1;
  const int r0 = blockIdx.y * 64;
  const int c0 = blockIdx.x * 64;

  const f32x4_t zero = {0.f, 0.f, 0.f, 0.f};
  f32x4_t acc[2][2];
#pragma unroll
  for (int m = 0; m < 2; ++m)
#pragma unroll
    for (int n = 0; n < 2; ++n) acc[m][n] = zero;

  for (int k0 = 0; k0 < K; k0 += 64) {
#pragma unroll
    for (int j = 0; j < 2; ++j) {
      const int c = tid + 256 * j;
      const int row = c >> 3;
      const int kk = c & 7;
      const int k16 = kk ^ (row & 7);
      GLL(Aop + (size_t)(r0 + row) * K + k0 + k16 * 8, Atile + c * 8);
      GLL(BT + (size_t)(c0 + row) * K + k0 + k16 * 8, Btile + c * 8);
    }
    __syncthreads();
#pragma unroll
    for (int kh = 0; kh < 2; ++kh) {
      bf16x8_t af[2], bfv[2];
#pragma unroll
      for (int m = 0; m < 2; ++m) {
        const int row = wr * 32 + m * 16 + (lane & 15);
        const int k16 = kh * 4 + (lane >> 4);
        af[m] = *(const bf16x8_t*)(Atile + (row * 8 + (k16 ^ (row & 7))) * 8);
      }
#pragma unroll
      for (int n = 0; n < 2; ++n) {
        const int row = wc * 32 + n * 16 + (lane & 15);
        const int k16 = kh * 4 + (lane >> 4);
        bfv[n] = *(const bf16x8_t*)(Btile + (row * 8 + (k16 ^ (row & 7))) * 8);
      }
#pragma unroll
      for (int m = 0; m < 2; ++m)
#pragma unroll
        for (int n = 0; n < 2; ++n)
          acc[m][n] = __builtin_amdgcn_mfma_f32_16x16x32_bf16(af[m], bfv[n],
                                                              acc[m][n], 0, 0, 0);
    }
    __syncthreads();
  }

  const int rbase = r0 + wr * 32 + ((lane >> 4) << 2);
  const int cbase = c0 + wc * 32 + (lane & 15);
#pragma unroll
  for (int m = 0; m < 2; ++m)
#pragma unroll
    for (int n = 0; n < 2; ++n)
#pragma unroll
      for (int q = 0; q < 4; ++q) {
        const size_t idx = (size_t)(rbase + m * 16 + q) * N + (cbase + n * 16);
        const float v = acc[m][n][q];
        if (CD_F32) ((float*)Cout)[idx] = v;
        else ((unsigned short*)Cout)[idx] = f2bf(v);
      }
}

// ------- 128^2 big-GEMM kernel, (256,4) + XCD swizzle, 32x32x16 MFMA -------
// A/B fragment (extrapolated from verified 16x16x32 family pattern):
//   lane holds row = lane&31, k = 8*(lane>>5) + e (8 contiguous bf16).
// C/D (HW-verified m74/m101): col = lane&31,
//   row = (reg&3) + 8*(reg>>2) + 4*(lane>>5), reg in [0,16).
template <int CD_F32, int STAGE_MODE>
__global__ __launch_bounds__(256, 4)
void gemm_big_k(const unsigned short* __restrict__ Aop,
                const unsigned short* __restrict__ BT,
                void* __restrict__ Cout,
                const unsigned short* __restrict__ addend,
                int M, int N, int K, int shift, int nbx) {
  __shared__ unsigned short Atile[128 * 64];
  __shared__ unsigned short Btile[128 * 64];
  const int tid = threadIdx.x;
  const int lane = tid & 63;
  const int w = tid >> 6;
  const int wr = w >> 1, wc = w & 1;
  const int hi = lane >> 5;
  const int rl = lane & 31;

  // XCD-bijective swizzle (nwg % 8 == 0) (T1).
  const int cpx = gridDim.x >> 3;
  const int id = blockIdx.x;
  const int swz = (id & 7) * cpx + (id >> 3);
  const int bx = swz % nbx;
  const int by = swz / nbx;
  const int r0 = by * 128;
  const int c0 = bx * 128;

  const f32x16_t zero16 = {0.f, 0.f, 0.f, 0.f, 0.f, 0.f, 0.f, 0.f,
                           0.f, 0.f, 0.f, 0.f, 0.f, 0.f, 0.f, 0.f};
  f32x16_t acc[2][2];
#pragma unroll
  for (int m = 0; m < 2; ++m)
#pragma unroll
    for (int n = 0; n < 2; ++n) acc[m][n] = zero16;

  // Fragment row indices (fixed per thread).
  const int rA0 = wr * 64 + rl, rA1 = rA0 + 32;
  const int rB0 = wc * 64 + rl, rB1 = rB0 + 32;

  for (int k0 = 0; k0 < K; k0 += 64) {
#pragma unroll
    for (int j = 0; j < 4; ++j) {
      const int c = tid + 256 * j;
      const int row = c >> 3;
      const int kk = c & 7;
      const int k16 = kk ^ (row & 7);
      GLL(Aop + (size_t)(r0 + row) * K + k0 + k16 * 8, Atile + c * 8);
      GLL(BT + (size_t)(c0 + row) * K + k0 + k16 * 8, Btile + c * 8);
    }
    __syncthreads();
#pragma unroll
    for (int ks = 0; ks < 4; ++ks) {
      const int c = ks * 2 + hi;  // logical 8-short chunk for this k-step
      bf16x8_t a0 = *(const bf16x8_t*)(Atile + (rA0 * 8 + (c ^ (rA0 & 7))) * 8);
      bf16x8_t a1 = *(const bf16x8_t*)(Atile + (rA1 * 8 + (c ^ (rA1 & 7))) * 8);
      bf16x8_t b0 = *(const bf16x8_t*)(Btile + (rB0 * 8 + (c ^ (rB0 & 7))) * 8);
      bf16x8_t b1 = *(const bf16x8_t*)(Btile + (rB1 * 8 + (c ^ (rB1 & 7))) * 8);
      acc[0][0] = __builtin_amdgcn_mfma_f32_32x32x16_bf16(a0, b0, acc[0][0], 0, 0, 0);
      acc[0][1] = __builtin_amdgcn_mfma_f32_32x32x16_bf16(a0, b1, acc[0][1], 0, 0, 0);
      acc[1][0] = __builtin_amdgcn_mfma_f32_32x32x16_bf16(a1, b0, acc[1][0], 0, 0, 0);
      acc[1][1] = __builtin_amdgcn_mfma_f32_32x32x16_bf16(a1, b1, acc[1][1], 0, 0, 0);
    }
    __syncthreads();
  }

  if (STAGE_MODE == 0) {
#pragma unroll
    for (int m = 0; m < 2; ++m)
#pragma unroll
      for (int n = 0; n < 2; ++n)
#pragma unroll
        for (int rg = 0; rg < 16; ++rg) {
          const int row = r0 + wr * 64 + m * 32 + (rg & 3) + 8 * (rg >> 2) + 4 * hi;
          const size_t idx = (size_t)row * N + (c0 + wc * 64 + n * 32 + rl);
          const float v = acc[m][n][rg];
          if (CD_F32) ((float*)Cout)[idx] = v;
          else ((unsigned short*)Cout)[idx] = f2bf(v);
        }
  } else {
#pragma unroll
    for (int m = 0; m < 2; ++m)
#pragma unroll
      for (int n = 0; n < 2; ++n)
#pragma unroll
        for (int rg = 0; rg < 16; ++rg) {
          const int orow =
              r0 + wr * 64 + m * 32 + (rg & 3) + 8 * (rg >> 2) + 4 * hi + shift;
          if (orow < M) {
            const size_t idx = (size_t)orow * N + (c0 + wc * 64 + n * 32 + rl);
            const float v = acc[m][n][rg] + bf2f(addend[idx]);
            if (CD_F32) ((float*)Cout)[idx] = v;
            else ((unsigned short*)Cout)[idx] = f2bf(v);
          }
        }
    if (by == 0) {  // rows [0, shift): pass-through of addend
      for (int i2 = tid; i2 < shift * 128; i2 += 256) {
        const int t = i2 >> 7;
        const size_t idx = (size_t)t * N + c0 + (i2 & 127);
        if (CD_F32) ((float*)Cout)[idx] = bf2f(addend[idx]);
        else ((unsigned short*)Cout)[idx] = addend[idx];
      }
    }
  }
}

extern "C" void kernel_launch(void* const* d_in, const int* in_sizes, int n_in,
                              void* d_out, int out_size, void* d_ws, size_t ws_size,
                              hipStream_t stream) {
  const float* X  = (const float*)d_in[0];   // (T,H)
  const float* Am = (const float*)d_in[1];   // (H,H)
  const float* Bm = (const float*)d_in[2];   // (H,H)

  const size_t TH = (size_t)TDIM * HDIM;
  const size_t HH = (size_t)HDIM * HDIM;

  unsigned short* Ua = (unsigned short*)d_out;  // bf16 ping inside d_out
  unsigned short* w = (unsigned short*)d_ws;
  size_t o = 0;
  unsigned short* Ub  = w + o; o += TH;  // pong (ws); also holds X-cast
  unsigned short* BTt = w + o; o += HH;
  unsigned short* P1  = w + o; o += HH;
  unsigned short* P1t = w + o; o += HH;
  unsigned short* P2  = w + o; o += HH;
  unsigned short* P2t = w + o; o += HH;
  unsigned short* P4  = w + o; o += HH;
  unsigned short* P4t = w + o; o += HH;
  unsigned short* P8  = w + o; o += HH;

  dim3 blk(256);
  dim3 gtr(64, 64);
  const int NBX = HDIM / 128;                 // 16
  dim3 gTbig((TDIM / 128) * NBX);             // 2048 blocks, 1-D
  dim3 g64(HDIM / 64, HDIM / 64);             // squarings: 32x32 = 1024 blocks

  // Casts / transposes.
  cast_f32_bf16_k<<<2048, blk, 0, stream>>>(X, Ub, (int)(TH / 4));
  cast_f32_bf16_k<<<512, blk, 0, stream>>>(Am, P1, (int)(HH / 4));
  transpose_cast_f32_k<<<gtr, blk, 0, stream>>>(Am, P1t, HDIM);
  transpose_cast_f32_k<<<gtr, blk, 0, stream>>>(Bm, BTt, HDIM);

  // U0 = X @ B  -> Ua (d_out bf16 region)
  gemm_big_k<0, 0><<<gTbig, blk, 0, stream>>>(Ub, BTt, Ua, nullptr,
                                              TDIM, HDIM, HDIM, 0, NBX);

  // Power chain: P2, P4, P8 (A^2, A^4, A^8) on the 64^2 TLP kernel.
  gemm64_k<0><<<g64, blk, 0, stream>>>(P1, P1t, P2, HDIM, HDIM);
  transpose_bf16_k<<<gtr, blk, 0, stream>>>(P2, P2t, HDIM);
  gemm64_k<0><<<g64, blk, 0, stream>>>(P2, P2t, P4, HDIM, HDIM);
  transpose_bf16_k<<<gtr, blk, 0, stream>>>(P4, P4t, HDIM);
  gemm64_k<0><<<g64, blk, 0, stream>>>(P4, P4t, P8, HDIM, HDIM);

  // Doubling stages (window 16): s = 1, 2, 4, 8.
  gemm_big_k<0, 1><<<gTbig, blk, 0, stream>>>(Ua, P1, Ub, Ua, TDIM, HDIM, HDIM, 1, NBX);
  gemm_big_k<0, 1><<<gTbig, blk, 0, stream>>>(Ub, P2, Ua, Ub, TDIM, HDIM, HDIM, 2, NBX);
  gemm_big_k<0, 1><<<gTbig, blk, 0, stream>>>(Ua, P4, Ub, Ua, TDIM, HDIM, HDIM, 4, NBX);
  // Final stage: fp32 accumulate + fp32 write straight into d_out.
  gemm_big_k<1, 1><<<gTbig, blk, 0, stream>>>(Ub, P8, d_out, Ub, TDIM, HDIM, HDIM, 8, NBX);

  (void)in_sizes; (void)n_in; (void)out_size; (void)ws_size;
}

// Round 9
// 903.425 us; speedup vs baseline: 1.0835x; 1.0835x over previous
//
#include <hip/hip_runtime.h>
#include <hip/hip_bf16.h>

// SSM h_t = A h_{t-1} + B^T x_t via stride-doubling over time, window 16:
//   U = X @ B;  u^k[t] = u^{k-1}[t] + u^{k-1}[t-s] @ (A^s)^T, s = 1,2,4,8
// Stage GEMMs: proven r7 kernel = m97 128^2/BK=64, 16x16x32 MFMA, (256,4)
//   forced 4 blocks/CU TLP + XCD swizzle (155.5 us, 884 TF, 0 conflicts).
// U-GEMM: 32x32x16 variant testing the quad-conflict theory (r8 post-mortem):
//   LDS b128 served as lane-quads (l,l+16,l+32,l+48); swizzle must separate
//   rows differing in bit 4 -> chunk ^ (row&7) ^ (((row>>4)&1)<<1).
// Squarings: 64^2-tile (256,4) kernel, 1024 blocks (r8 tail win: 120->64 us).

typedef __attribute__((ext_vector_type(8))) short bf16x8_t;
typedef __attribute__((ext_vector_type(4))) float f32x4_t;
typedef __attribute__((ext_vector_type(16))) float f32x16_t;
typedef __attribute__((ext_vector_type(4))) float float4_t;
typedef __attribute__((ext_vector_type(4))) unsigned short ushort4_t;

#define TDIM 16384
#define HDIM 2048

__device__ __forceinline__ unsigned short f2bf(float f) {
  unsigned int x = __builtin_bit_cast(unsigned int, f);
  x += 0x7fffu + ((x >> 16) & 1u);
  return (unsigned short)(x >> 16);
}
__device__ __forceinline__ float bf2f(unsigned short u) {
  unsigned int x = ((unsigned int)u) << 16;
  return __builtin_bit_cast(float, x);
}

__global__ void cast_f32_bf16_k(const float* __restrict__ in,
                                unsigned short* __restrict__ out, int n4) {
  int i = blockIdx.x * blockDim.x + threadIdx.x;
  const int stride = gridDim.x * blockDim.x;
  for (; i < n4; i += stride) {
    float4_t v = ((const float4_t*)in)[i];
    ushort4_t o;
    o[0] = f2bf(v[0]); o[1] = f2bf(v[1]); o[2] = f2bf(v[2]); o[3] = f2bf(v[3]);
    ((ushort4_t*)out)[i] = o;
  }
}

__global__ void transpose_cast_f32_k(const float* __restrict__ in,
                                     unsigned short* __restrict__ out, int n) {
  __shared__ unsigned short tile[32][33];
  const int tx = threadIdx.x & 31, ty = threadIdx.x >> 5;
  const int bx = blockIdx.x * 32, by = blockIdx.y * 32;
#pragma unroll
  for (int j = 0; j < 32; j += 8)
    tile[ty + j][tx] = f2bf(in[(size_t)(by + ty + j) * n + bx + tx]);
  __syncthreads();
#pragma unroll
  for (int j = 0; j < 32; j += 8)
    out[(size_t)(bx + ty + j) * n + by + tx] = tile[tx][ty + j];
}

__global__ void transpose_bf16_k(const unsigned short* __restrict__ in,
                                 unsigned short* __restrict__ out, int n) {
  __shared__ unsigned short tile[32][33];
  const int tx = threadIdx.x & 31, ty = threadIdx.x >> 5;
  const int bx = blockIdx.x * 32, by = blockIdx.y * 32;
#pragma unroll
  for (int j = 0; j < 32; j += 8)
    tile[ty + j][tx] = in[(size_t)(by + ty + j) * n + bx + tx];
  __syncthreads();
#pragma unroll
  for (int j = 0; j < 32; j += 8)
    out[(size_t)(bx + ty + j) * n + by + tx] = tile[tx][ty + j];
}

#define GLL(SRC, DST)                                                          \
  __builtin_amdgcn_global_load_lds(                                            \
      (const __attribute__((address_space(1))) unsigned int*)(SRC),            \
      (__attribute__((address_space(3))) unsigned int*)(DST), 16, 0, 0)

// ------------- 64^2-tile kernel, (256,4): H x H squarings -------------
template <int CD_F32>
__global__ __launch_bounds__(256, 4)
void gemm64_k(const unsigned short* __restrict__ Aop,
              const unsigned short* __restrict__ BT,
              void* __restrict__ Cout, int N, int K) {
  __shared__ unsigned short Atile[64 * 64];
  __shared__ unsigned short Btile[64 * 64];
  const int tid = threadIdx.x;
  const int lane = tid & 63;
  const int w = tid >> 6;
  const int wr = w >> 1, wc = w & 1;
  const int r0 = blockIdx.y * 64;
  const int c0 = blockIdx.x * 64;

  const f32x4_t zero = {0.f, 0.f, 0.f, 0.f};
  f32x4_t acc[2][2];
#pragma unroll
  for (int m = 0; m < 2; ++m)
#pragma unroll
    for (int n = 0; n < 2; ++n) acc[m][n] = zero;

  for (int k0 = 0; k0 < K; k0 += 64) {
#pragma unroll
    for (int j = 0; j < 2; ++j) {
      const int c = tid + 256 * j;
      const int row = c >> 3;
      const int kk = c & 7;
      const int k16 = kk ^ (row & 7);
      GLL(Aop + (size_t)(r0 + row) * K + k0 + k16 * 8, Atile + c * 8);
      GLL(BT + (size_t)(c0 + row) * K + k0 + k16 * 8, Btile + c * 8);
    }
    __syncthreads();
#pragma unroll
    for (int kh = 0; kh < 2; ++kh) {
      bf16x8_t af[2], bfv[2];
#pragma unroll
      for (int m = 0; m < 2; ++m) {
        const int row = wr * 32 + m * 16 + (lane & 15);
        const int k16 = kh * 4 + (lane >> 4);
        af[m] = *(const bf16x8_t*)(Atile + (row * 8 + (k16 ^ (row & 7))) * 8);
      }
#pragma unroll
      for (int n = 0; n < 2; ++n) {
        const int row = wc * 32 + n * 16 + (lane & 15);
        const int k16 = kh * 4 + (lane >> 4);
        bfv[n] = *(const bf16x8_t*)(Btile + (row * 8 + (k16 ^ (row & 7))) * 8);
      }
#pragma unroll
      for (int m = 0; m < 2; ++m)
#pragma unroll
        for (int n = 0; n < 2; ++n)
          acc[m][n] = __builtin_amdgcn_mfma_f32_16x16x32_bf16(af[m], bfv[n],
                                                              acc[m][n], 0, 0, 0);
    }
    __syncthreads();
  }

  const int rbase = r0 + wr * 32 + ((lane >> 4) << 2);
  const int cbase = c0 + wc * 32 + (lane & 15);
#pragma unroll
  for (int m = 0; m < 2; ++m)
#pragma unroll
    for (int n = 0; n < 2; ++n)
#pragma unroll
      for (int q = 0; q < 4; ++q) {
        const size_t idx = (size_t)(rbase + m * 16 + q) * N + (cbase + n * 16);
        const float v = acc[m][n][q];
        if (CD_F32) ((float*)Cout)[idx] = v;
        else ((unsigned short*)Cout)[idx] = f2bf(v);
      }
}

// ------- 128^2 stage-GEMM kernel (r7 proven): 16x16x32, (256,4) + swizzle ---
template <int CD_F32, int STAGE_MODE>
__global__ __launch_bounds__(256, 4)
void gemm_big_k(const unsigned short* __restrict__ Aop,
                const unsigned short* __restrict__ BT,
                void* __restrict__ Cout,
                const unsigned short* __restrict__ addend,
                int M, int N, int K, int shift, int nbx) {
  __shared__ unsigned short Atile[128 * 64];
  __shared__ unsigned short Btile[128 * 64];
  const int tid = threadIdx.x;
  const int lane = tid & 63;
  const int w = tid >> 6;
  const int wr = w >> 1, wc = w & 1;

  const int cpx = gridDim.x >> 3;
  const int id = blockIdx.x;
  const int swz = (id & 7) * cpx + (id >> 3);
  const int bx = swz % nbx;
  const int by = swz / nbx;
  const int r0 = by * 128;
  const int c0 = bx * 128;

  const f32x4_t zero = {0.f, 0.f, 0.f, 0.f};
  f32x4_t acc[4][4];
#pragma unroll
  for (int m = 0; m < 4; ++m)
#pragma unroll
    for (int n = 0; n < 4; ++n) acc[m][n] = zero;

  for (int k0 = 0; k0 < K; k0 += 64) {
#pragma unroll
    for (int j = 0; j < 4; ++j) {
      const int c = tid + 256 * j;
      const int row = c >> 3;
      const int kk = c & 7;
      const int k16 = kk ^ (row & 7);
      GLL(Aop + (size_t)(r0 + row) * K + k0 + k16 * 8, Atile + c * 8);
      GLL(BT + (size_t)(c0 + row) * K + k0 + k16 * 8, Btile + c * 8);
    }
    __syncthreads();
#pragma unroll
    for (int kh = 0; kh < 2; ++kh) {
      bf16x8_t af[4], bfv[4];
#pragma unroll
      for (int m = 0; m < 4; ++m) {
        const int row = wr * 64 + m * 16 + (lane & 15);
        const int k16 = kh * 4 + (lane >> 4);
        af[m] = *(const bf16x8_t*)(Atile + (row * 8 + (k16 ^ (row & 7))) * 8);
      }
#pragma unroll
      for (int n = 0; n < 4; ++n) {
        const int row = wc * 64 + n * 16 + (lane & 15);
        const int k16 = kh * 4 + (lane >> 4);
        bfv[n] = *(const bf16x8_t*)(Btile + (row * 8 + (k16 ^ (row & 7))) * 8);
      }
#pragma unroll
      for (int m = 0; m < 4; ++m)
#pragma unroll
        for (int n = 0; n < 4; ++n)
          acc[m][n] = __builtin_amdgcn_mfma_f32_16x16x32_bf16(af[m], bfv[n],
                                                              acc[m][n], 0, 0, 0);
    }
    __syncthreads();
  }

  // C/D layout: col = lane&15, row = (lane>>4)*4 + q (m89/m91 verified).
  const int rbase = r0 + wr * 64 + ((lane >> 4) << 2);
  const int cbase = c0 + wc * 64 + (lane & 15);
  if (STAGE_MODE == 0) {
#pragma unroll
    for (int m = 0; m < 4; ++m)
#pragma unroll
      for (int n = 0; n < 4; ++n)
#pragma unroll
        for (int q = 0; q < 4; ++q) {
          const size_t idx = (size_t)(rbase + m * 16 + q) * N + (cbase + n * 16);
          const float v = acc[m][n][q];
          if (CD_F32) ((float*)Cout)[idx] = v;
          else ((unsigned short*)Cout)[idx] = f2bf(v);
        }
  } else {
#pragma unroll
    for (int m = 0; m < 4; ++m)
#pragma unroll
      for (int n = 0; n < 4; ++n)
#pragma unroll
        for (int q = 0; q < 4; ++q) {
          const int orow = rbase + m * 16 + q + shift;
          if (orow < M) {
            const size_t idx = (size_t)orow * N + (cbase + n * 16);
            const float v = acc[m][n][q] + bf2f(addend[idx]);
            if (CD_F32) ((float*)Cout)[idx] = v;
            else ((unsigned short*)Cout)[idx] = f2bf(v);
          }
        }
    if (by == 0) {  // rows [0, shift): pass-through of addend
      for (int i2 = tid; i2 < shift * 128; i2 += 256) {
        const int t = i2 >> 7;
        const size_t idx = (size_t)t * N + c0 + (i2 & 127);
        if (CD_F32) ((float*)Cout)[idx] = bf2f(addend[idx]);
        else ((unsigned short*)Cout)[idx] = addend[idx];
      }
    }
  }
}

// ---- 128^2 U-GEMM kernel: 32x32x16 MFMA + quad-fixed swizzle (experiment) --
// Swizzle g(row) = (row&7) ^ (((row>>4)&1)<<1): lane-quads (l,l+16,l+32,l+48)
// get slots base^{0,1,2,3} (distinct); 8-consecutive lane groups still span
// all 8 slots. Layout validated in r8 (absmax unchanged).
__global__ __launch_bounds__(256, 4)
void gemm_big32_k(const unsigned short* __restrict__ Aop,
                  const unsigned short* __restrict__ BT,
                  void* __restrict__ Cout,
                  int M, int N, int K, int nbx) {
  __shared__ unsigned short Atile[128 * 64];
  __shared__ unsigned short Btile[128 * 64];
  const int tid = threadIdx.x;
  const int lane = tid & 63;
  const int w = tid >> 6;
  const int wr = w >> 1, wc = w & 1;
  const int hi = lane >> 5;
  const int rl = lane & 31;

  const int cpx = gridDim.x >> 3;
  const int id = blockIdx.x;
  const int swz = (id & 7) * cpx + (id >> 3);
  const int bx = swz % nbx;
  const int by = swz / nbx;
  const int r0 = by * 128;
  const int c0 = bx * 128;

  const f32x16_t zero16 = {0.f, 0.f, 0.f, 0.f, 0.f, 0.f, 0.f, 0.f,
                           0.f, 0.f, 0.f, 0.f, 0.f, 0.f, 0.f, 0.f};
  f32x16_t acc[2][2];
#pragma unroll
  for (int m = 0; m < 2; ++m)
#pragma unroll
    for (int n = 0; n < 2; ++n) acc[m][n] = zero16;

  const int rA0 = wr * 64 + rl, rA1 = rA0 + 32;
  const int rB0 = wc * 64 + rl, rB1 = rB0 + 32;
  const int gA0 = (rA0 & 7) ^ (((rA0 >> 4) & 1) << 1);
  const int gA1 = (rA1 & 7) ^ (((rA1 >> 4) & 1) << 1);
  const int gB0 = (rB0 & 7) ^ (((rB0 >> 4) & 1) << 1);
  const int gB1 = (rB1 & 7) ^ (((rB1 >> 4) & 1) << 1);

  for (int k0 = 0; k0 < K; k0 += 64) {
#pragma unroll
    for (int j = 0; j < 4; ++j) {
      const int c = tid + 256 * j;
      const int row = c >> 3;
      const int kk = c & 7;
      const int k16 = kk ^ (row & 7) ^ (((row >> 4) & 1) << 1);
      GLL(Aop + (size_t)(r0 + row) * K + k0 + k16 * 8, Atile + c * 8);
      GLL(BT + (size_t)(c0 + row) * K + k0 + k16 * 8, Btile + c * 8);
    }
    __syncthreads();
#pragma unroll
    for (int ks = 0; ks < 4; ++ks) {
      const int c = ks * 2 + hi;
      bf16x8_t a0 = *(const bf16x8_t*)(Atile + (rA0 * 8 + (c ^ gA0)) * 8);
      bf16x8_t a1 = *(const bf16x8_t*)(Atile + (rA1 * 8 + (c ^ gA1)) * 8);
      bf16x8_t b0 = *(const bf16x8_t*)(Btile + (rB0 * 8 + (c ^ gB0)) * 8);
      bf16x8_t b1 = *(const bf16x8_t*)(Btile + (rB1 * 8 + (c ^ gB1)) * 8);
      acc[0][0] = __builtin_amdgcn_mfma_f32_32x32x16_bf16(a0, b0, acc[0][0], 0, 0, 0);
      acc[0][1] = __builtin_amdgcn_mfma_f32_32x32x16_bf16(a0, b1, acc[0][1], 0, 0, 0);
      acc[1][0] = __builtin_amdgcn_mfma_f32_32x32x16_bf16(a1, b0, acc[1][0], 0, 0, 0);
      acc[1][1] = __builtin_amdgcn_mfma_f32_32x32x16_bf16(a1, b1, acc[1][1], 0, 0, 0);
    }
    __syncthreads();
  }

  // C/D (HW-verified m74/m101): col = lane&31, row = (rg&3)+8*(rg>>2)+4*hi.
#pragma unroll
  for (int m = 0; m < 2; ++m)
#pragma unroll
    for (int n = 0; n < 2; ++n)
#pragma unroll
      for (int rg = 0; rg < 16; ++rg) {
        const int row = r0 + wr * 64 + m * 32 + (rg & 3) + 8 * (rg >> 2) + 4 * hi;
        const size_t idx = (size_t)row * N + (c0 + wc * 64 + n * 32 + rl);
        ((unsigned short*)Cout)[idx] = f2bf(acc[m][n][rg]);
      }
}

extern "C" void kernel_launch(void* const* d_in, const int* in_sizes, int n_in,
                              void* d_out, int out_size, void* d_ws, size_t ws_size,
                              hipStream_t stream) {
  const float* X  = (const float*)d_in[0];   // (T,H)
  const float* Am = (const float*)d_in[1];   // (H,H)
  const float* Bm = (const float*)d_in[2];   // (H,H)

  const size_t TH = (size_t)TDIM * HDIM;
  const size_t HH = (size_t)HDIM * HDIM;

  unsigned short* Ua = (unsigned short*)d_out;  // bf16 ping inside d_out
  unsigned short* w = (unsigned short*)d_ws;
  size_t o = 0;
  unsigned short* Ub  = w + o; o += TH;  // pong (ws); also holds X-cast
  unsigned short* BTt = w + o; o += HH;
  unsigned short* P1  = w + o; o += HH;
  unsigned short* P1t = w + o; o += HH;
  unsigned short* P2  = w + o; o += HH;
  unsigned short* P2t = w + o; o += HH;
  unsigned short* P4  = w + o; o += HH;
  unsigned short* P4t = w + o; o += HH;
  unsigned short* P8  = w + o; o += HH;

  dim3 blk(256);
  dim3 gtr(64, 64);
  const int NBX = HDIM / 128;                 // 16
  dim3 gTbig((TDIM / 128) * NBX);             // 2048 blocks, 1-D
  dim3 g64(HDIM / 64, HDIM / 64);             // squarings: 1024 blocks

  // Casts / transposes.
  cast_f32_bf16_k<<<2048, blk, 0, stream>>>(X, Ub, (int)(TH / 4));
  cast_f32_bf16_k<<<512, blk, 0, stream>>>(Am, P1, (int)(HH / 4));
  transpose_cast_f32_k<<<gtr, blk, 0, stream>>>(Am, P1t, HDIM);
  transpose_cast_f32_k<<<gtr, blk, 0, stream>>>(Bm, BTt, HDIM);

  // U0 = X @ B -> Ua  [32x32 quad-swizzle experiment dispatch]
  gemm_big32_k<<<gTbig, blk, 0, stream>>>(Ub, BTt, Ua, TDIM, HDIM, HDIM, NBX);

  // Power chain: P2, P4, P8 (A^2, A^4, A^8) on the 64^2 TLP kernel.
  gemm64_k<0><<<g64, blk, 0, stream>>>(P1, P1t, P2, HDIM, HDIM);
  transpose_bf16_k<<<gtr, blk, 0, stream>>>(P2, P2t, HDIM);
  gemm64_k<0><<<g64, blk, 0, stream>>>(P2, P2t, P4, HDIM, HDIM);
  transpose_bf16_k<<<gtr, blk, 0, stream>>>(P4, P4t, HDIM);
  gemm64_k<0><<<g64, blk, 0, stream>>>(P4, P4t, P8, HDIM, HDIM);

  // Doubling stages (window 16): s = 1, 2, 4, 8  [proven 16x16 kernel].
  gemm_big_k<0, 1><<<gTbig, blk, 0, stream>>>(Ua, P1, Ub, Ua, TDIM, HDIM, HDIM, 1, NBX);
  gemm_big_k<0, 1><<<gTbig, blk, 0, stream>>>(Ub, P2, Ua, Ub, TDIM, HDIM, HDIM, 2, NBX);
  gemm_big_k<0, 1><<<gTbig, blk, 0, stream>>>(Ua, P4, Ub, Ua, TDIM, HDIM, HDIM, 4, NBX);
  // Final stage: fp32 accumulate + fp32 write straight into d_out.
  gemm_big_k<1, 1><<<gTbig, blk, 0, stream>>>(Ub, P8, d_out, Ub, TDIM, HDIM, HDIM, 8, NBX);

  (void)in_sizes; (void)n_in; (void)out_size; (void)ws_size;
}

// Round 10
// 878.327 us; speedup vs baseline: 1.1145x; 1.0286x over previous
//
#include <hip/hip_runtime.h>
#include <hip/hip_bf16.h>

// SSM h_t = A h_{t-1} + B^T x_t via stride-doubling over time, window 16:
//   U = X @ B;  u^k[t] = u^{k-1}[t] + u^{k-1}[t-s] @ (A^s)^T, s = 1,2,4,8
//   h = u^4  (window-16 truncation bit-invisible vs bf16 noise: r1==r5..r9)
// All five big GEMMs (16384x2048x2048): proven m97 128^2/BK=64 16x16x32
//   kernel at (256,4) forced 4 blocks/CU TLP + XCD-bijective swizzle.
//   Measured 155.5-157 us each (881 TF), 0 bank conflicts, MfmaUtil 39% --
//   at ~97% of this structure's LDS-BW ceiling (fragment reads + DMA writes
//   ~1540 cyc/CU/K-tile vs 620 cyc MFMA -> 40% cap). 32x32 variant retired
//   (r8: +4cyc/read quad conflicts; r9: quad-fix swizzle did not recover).
// Squarings (2048^3): 64^2-tile (256,4) kernel, 1024 blocks (r8 tail win).

typedef __attribute__((ext_vector_type(8))) short bf16x8_t;
typedef __attribute__((ext_vector_type(4))) float f32x4_t;
typedef __attribute__((ext_vector_type(4))) float float4_t;
typedef __attribute__((ext_vector_type(4))) unsigned short ushort4_t;

#define TDIM 16384
#define HDIM 2048

__device__ __forceinline__ unsigned short f2bf(float f) {
  unsigned int x = __builtin_bit_cast(unsigned int, f);
  x += 0x7fffu + ((x >> 16) & 1u);
  return (unsigned short)(x >> 16);
}
__device__ __forceinline__ float bf2f(unsigned short u) {
  unsigned int x = ((unsigned int)u) << 16;
  return __builtin_bit_cast(float, x);
}

__global__ void cast_f32_bf16_k(const float* __restrict__ in,
                                unsigned short* __restrict__ out, int n4) {
  int i = blockIdx.x * blockDim.x + threadIdx.x;
  const int stride = gridDim.x * blockDim.x;
  for (; i < n4; i += stride) {
    float4_t v = ((const float4_t*)in)[i];
    ushort4_t o;
    o[0] = f2bf(v[0]); o[1] = f2bf(v[1]); o[2] = f2bf(v[2]); o[3] = f2bf(v[3]);
    ((ushort4_t*)out)[i] = o;
  }
}

__global__ void transpose_cast_f32_k(const float* __restrict__ in,
                                     unsigned short* __restrict__ out, int n) {
  __shared__ unsigned short tile[32][33];
  const int tx = threadIdx.x & 31, ty = threadIdx.x >> 5;
  const int bx = blockIdx.x * 32, by = blockIdx.y * 32;
#pragma unroll
  for (int j = 0; j < 32; j += 8)
    tile[ty + j][tx] = f2bf(in[(size_t)(by + ty + j) * n + bx + tx]);
  __syncthreads();
#pragma unroll
  for (int j = 0; j < 32; j += 8)
    out[(size_t)(bx + ty + j) * n + by + tx] = tile[tx][ty + j];
}

__global__ void transpose_bf16_k(const unsigned short* __restrict__ in,
                                 unsigned short* __restrict__ out, int n) {
  __shared__ unsigned short tile[32][33];
  const int tx = threadIdx.x & 31, ty = threadIdx.x >> 5;
  const int bx = blockIdx.x * 32, by = blockIdx.y * 32;
#pragma unroll
  for (int j = 0; j < 32; j += 8)
    tile[ty + j][tx] = in[(size_t)(by + ty + j) * n + bx + tx];
  __syncthreads();
#pragma unroll
  for (int j = 0; j < 32; j += 8)
    out[(size_t)(bx + ty + j) * n + by + tx] = tile[tx][ty + j];
}

#define GLL(SRC, DST)                                                          \
  __builtin_amdgcn_global_load_lds(                                            \
      (const __attribute__((address_space(1))) unsigned int*)(SRC),            \
      (__attribute__((address_space(3))) unsigned int*)(DST), 16, 0, 0)

// ------------- 64^2-tile kernel, (256,4): H x H squarings -------------
template <int CD_F32>
__global__ __launch_bounds__(256, 4)
void gemm64_k(const unsigned short* __restrict__ Aop,
              const unsigned short* __restrict__ BT,
              void* __restrict__ Cout, int N, int K) {
  __shared__ unsigned short Atile[64 * 64];
  __shared__ unsigned short Btile[64 * 64];
  const int tid = threadIdx.x;
  const int lane = tid & 63;
  const int w = tid >> 6;
  const int wr = w >> 1, wc = w & 1;
  const int r0 = blockIdx.y * 64;
  const int c0 = blockIdx.x * 64;

  const f32x4_t zero = {0.f, 0.f, 0.f, 0.f};
  f32x4_t acc[2][2];
#pragma unroll
  for (int m = 0; m < 2; ++m)
#pragma unroll
    for (int n = 0; n < 2; ++n) acc[m][n] = zero;

  for (int k0 = 0; k0 < K; k0 += 64) {
#pragma unroll
    for (int j = 0; j < 2; ++j) {
      const int c = tid + 256 * j;
      const int row = c >> 3;
      const int kk = c & 7;
      const int k16 = kk ^ (row & 7);
      GLL(Aop + (size_t)(r0 + row) * K + k0 + k16 * 8, Atile + c * 8);
      GLL(BT + (size_t)(c0 + row) * K + k0 + k16 * 8, Btile + c * 8);
    }
    __syncthreads();
#pragma unroll
    for (int kh = 0; kh < 2; ++kh) {
      bf16x8_t af[2], bfv[2];
#pragma unroll
      for (int m = 0; m < 2; ++m) {
        const int row = wr * 32 + m * 16 + (lane & 15);
        const int k16 = kh * 4 + (lane >> 4);
        af[m] = *(const bf16x8_t*)(Atile + (row * 8 + (k16 ^ (row & 7))) * 8);
      }
#pragma unroll
      for (int n = 0; n < 2; ++n) {
        const int row = wc * 32 + n * 16 + (lane & 15);
        const int k16 = kh * 4 + (lane >> 4);
        bfv[n] = *(const bf16x8_t*)(Btile + (row * 8 + (k16 ^ (row & 7))) * 8);
      }
#pragma unroll
      for (int m = 0; m < 2; ++m)
#pragma unroll
        for (int n = 0; n < 2; ++n)
          acc[m][n] = __builtin_amdgcn_mfma_f32_16x16x32_bf16(af[m], bfv[n],
                                                              acc[m][n], 0, 0, 0);
    }
    __syncthreads();
  }

  const int rbase = r0 + wr * 32 + ((lane >> 4) << 2);
  const int cbase = c0 + wc * 32 + (lane & 15);
#pragma unroll
  for (int m = 0; m < 2; ++m)
#pragma unroll
    for (int n = 0; n < 2; ++n)
#pragma unroll
      for (int q = 0; q < 4; ++q) {
        const size_t idx = (size_t)(rbase + m * 16 + q) * N + (cbase + n * 16);
        const float v = acc[m][n][q];
        if (CD_F32) ((float*)Cout)[idx] = v;
        else ((unsigned short*)Cout)[idx] = f2bf(v);
      }
}

// ------- 128^2 big-GEMM kernel (proven): 16x16x32, (256,4) + XCD swizzle ----
template <int CD_F32, int STAGE_MODE>
__global__ __launch_bounds__(256, 4)
void gemm_big_k(const unsigned short* __restrict__ Aop,
                const unsigned short* __restrict__ BT,
                void* __restrict__ Cout,
                const unsigned short* __restrict__ addend,
                int M, int N, int K, int shift, int nbx) {
  __shared__ unsigned short Atile[128 * 64];
  __shared__ unsigned short Btile[128 * 64];
  const int tid = threadIdx.x;
  const int lane = tid & 63;
  const int w = tid >> 6;
  const int wr = w >> 1, wc = w & 1;

  // XCD-bijective swizzle (nwg % 8 == 0) (T1).
  const int cpx = gridDim.x >> 3;
  const int id = blockIdx.x;
  const int swz = (id & 7) * cpx + (id >> 3);
  const int bx = swz % nbx;
  const int by = swz / nbx;
  const int r0 = by * 128;
  const int c0 = bx * 128;

  const f32x4_t zero = {0.f, 0.f, 0.f, 0.f};
  f32x4_t acc[4][4];
#pragma unroll
  for (int m = 0; m < 4; ++m)
#pragma unroll
    for (int n = 0; n < 4; ++n) acc[m][n] = zero;

  for (int k0 = 0; k0 < K; k0 += 64) {
#pragma unroll
    for (int j = 0; j < 4; ++j) {
      const int c = tid + 256 * j;
      const int row = c >> 3;
      const int kk = c & 7;
      const int k16 = kk ^ (row & 7);
      GLL(Aop + (size_t)(r0 + row) * K + k0 + k16 * 8, Atile + c * 8);
      GLL(BT + (size_t)(c0 + row) * K + k0 + k16 * 8, Btile + c * 8);
    }
    __syncthreads();
#pragma unroll
    for (int kh = 0; kh < 2; ++kh) {
      bf16x8_t af[4], bfv[4];
#pragma unroll
      for (int m = 0; m < 4; ++m) {
        const int row = wr * 64 + m * 16 + (lane & 15);
        const int k16 = kh * 4 + (lane >> 4);
        af[m] = *(const bf16x8_t*)(Atile + (row * 8 + (k16 ^ (row & 7))) * 8);
      }
#pragma unroll
      for (int n = 0; n < 4; ++n) {
        const int row = wc * 64 + n * 16 + (lane & 15);
        const int k16 = kh * 4 + (lane >> 4);
        bfv[n] = *(const bf16x8_t*)(Btile + (row * 8 + (k16 ^ (row & 7))) * 8);
      }
#pragma unroll
      for (int m = 0; m < 4; ++m)
#pragma unroll
        for (int n = 0; n < 4; ++n)
          acc[m][n] = __builtin_amdgcn_mfma_f32_16x16x32_bf16(af[m], bfv[n],
                                                              acc[m][n], 0, 0, 0);
    }
    __syncthreads();
  }

  // C/D layout: col = lane&15, row = (lane>>4)*4 + q (m89/m91 verified).
  const int rbase = r0 + wr * 64 + ((lane >> 4) << 2);
  const int cbase = c0 + wc * 64 + (lane & 15);
  if (STAGE_MODE == 0) {
#pragma unroll
    for (int m = 0; m < 4; ++m)
#pragma unroll
      for (int n = 0; n < 4; ++n)
#pragma unroll
        for (int q = 0; q < 4; ++q) {
          const size_t idx = (size_t)(rbase + m * 16 + q) * N + (cbase + n * 16);
          const float v = acc[m][n][q];
          if (CD_F32) ((float*)Cout)[idx] = v;
          else ((unsigned short*)Cout)[idx] = f2bf(v);
        }
  } else {
#pragma unroll
    for (int m = 0; m < 4; ++m)
#pragma unroll
      for (int n = 0; n < 4; ++n)
#pragma unroll
        for (int q = 0; q < 4; ++q) {
          const int orow = rbase + m * 16 + q + shift;
          if (orow < M) {
            const size_t idx = (size_t)orow * N + (cbase + n * 16);
            const float v = acc[m][n][q] + bf2f(addend[idx]);
            if (CD_F32) ((float*)Cout)[idx] = v;
            else ((unsigned short*)Cout)[idx] = f2bf(v);
          }
        }
    if (by == 0) {  // rows [0, shift): pass-through of addend
      for (int i2 = tid; i2 < shift * 128; i2 += 256) {
        const int t = i2 >> 7;
        const size_t idx = (size_t)t * N + c0 + (i2 & 127);
        if (CD_F32) ((float*)Cout)[idx] = bf2f(addend[idx]);
        else ((unsigned short*)Cout)[idx] = addend[idx];
      }
    }
  }
}

extern "C" void kernel_launch(void* const* d_in, const int* in_sizes, int n_in,
                              void* d_out, int out_size, void* d_ws, size_t ws_size,
                              hipStream_t stream) {
  const float* X  = (const float*)d_in[0];   // (T,H)
  const float* Am = (const float*)d_in[1];   // (H,H)
  const float* Bm = (const float*)d_in[2];   // (H,H)

  const size_t TH = (size_t)TDIM * HDIM;
  const size_t HH = (size_t)HDIM * HDIM;

  unsigned short* Ua = (unsigned short*)d_out;  // bf16 ping inside d_out
  unsigned short* w = (unsigned short*)d_ws;
  size_t o = 0;
  unsigned short* Ub  = w + o; o += TH;  // pong (ws); also holds X-cast
  unsigned short* BTt = w + o; o += HH;
  unsigned short* P1  = w + o; o += HH;
  unsigned short* P1t = w + o; o += HH;
  unsigned short* P2  = w + o; o += HH;
  unsigned short* P2t = w + o; o += HH;
  unsigned short* P4  = w + o; o += HH;
  unsigned short* P4t = w + o; o += HH;
  unsigned short* P8  = w + o; o += HH;

  dim3 blk(256);
  dim3 gtr(64, 64);
  const int NBX = HDIM / 128;                 // 16
  dim3 gTbig((TDIM / 128) * NBX);             // 2048 blocks, 1-D
  dim3 g64(HDIM / 64, HDIM / 64);             // squarings: 1024 blocks

  // Casts / transposes.
  cast_f32_bf16_k<<<2048, blk, 0, stream>>>(X, Ub, (int)(TH / 4));
  cast_f32_bf16_k<<<512, blk, 0, stream>>>(Am, P1, (int)(HH / 4));
  transpose_cast_f32_k<<<gtr, blk, 0, stream>>>(Am, P1t, HDIM);
  transpose_cast_f32_k<<<gtr, blk, 0, stream>>>(Bm, BTt, HDIM);

  // U0 = X @ B -> Ua (d_out bf16 region)  [proven 16x16 kernel]
  gemm_big_k<0, 0><<<gTbig, blk, 0, stream>>>(Ub, BTt, Ua, nullptr,
                                              TDIM, HDIM, HDIM, 0, NBX);

  // Power chain: P2, P4, P8 (A^2, A^4, A^8) on the 64^2 TLP kernel.
  gemm64_k<0><<<g64, blk, 0, stream>>>(P1, P1t, P2, HDIM, HDIM);
  transpose_bf16_k<<<gtr, blk, 0, stream>>>(P2, P2t, HDIM);
  gemm64_k<0><<<g64, blk, 0, stream>>>(P2, P2t, P4, HDIM, HDIM);
  transpose_bf16_k<<<gtr, blk, 0, stream>>>(P4, P4t, HDIM);
  gemm64_k<0><<<g64, blk, 0, stream>>>(P4, P4t, P8, HDIM, HDIM);

  // Doubling stages (window 16): s = 1, 2, 4, 8  [proven 16x16 kernel].
  gemm_big_k<0, 1><<<gTbig, blk, 0, stream>>>(Ua, P1, Ub, Ua, TDIM, HDIM, HDIM, 1, NBX);
  gemm_big_k<0, 1><<<gTbig, blk, 0, stream>>>(Ub, P2, Ua, Ub, TDIM, HDIM, HDIM, 2, NBX);
  gemm_big_k<0, 1><<<gTbig, blk, 0, stream>>>(Ua, P4, Ub, Ua, TDIM, HDIM, HDIM, 4, NBX);
  // Final stage: fp32 accumulate + fp32 write straight into d_out.
  gemm_big_k<1, 1><<<gTbig, blk, 0, stream>>>(Ub, P8, d_out, Ub, TDIM, HDIM, HDIM, 8, NBX);

  (void)in_sizes; (void)n_in; (void)out_size; (void)ws_size;
}